// Round 3
// baseline (710.038 us; speedup 1.0000x reference)
//
#include <hip/hip_runtime.h>

#define DD 256
#define TT 4096
#define BB 32

typedef __attribute__((ext_vector_type(8))) short short8;   // 8 bf16 (4 VGPR)
typedef __attribute__((ext_vector_type(4))) float floatx4;  // MFMA acc

// ---------- bf16 helpers (RNE via bit twiddle) ----------
__device__ __forceinline__ unsigned short f2bf(float f) {
    unsigned u = __builtin_bit_cast(unsigned, f);
    unsigned r = u + 0x7FFFu + ((u >> 16) & 1u);
    return (unsigned short)(r >> 16);
}
__device__ __forceinline__ float bf2f(unsigned short h) {
    return __builtin_bit_cast(float, (unsigned)h << 16);
}
__device__ __forceinline__ float2 unpk(unsigned u) {
    float2 r;
    r.x = __builtin_bit_cast(float, u << 16);
    r.y = __builtin_bit_cast(float, u & 0xFFFF0000u);
    return r;
}

#define GLDS16(g, l)                                                        \
    __builtin_amdgcn_global_load_lds(                                       \
        (const __attribute__((address_space(1))) void*)(g),                 \
        (__attribute__((address_space(3))) void*)(l), 16, 0, 0)

// ======================= X prep: fp32 -> bf16 ==============================
__global__ __launch_bounds__(256)
void prep_x_kernel(const float* __restrict__ X, unsigned short* __restrict__ Xh)
{
    size_t i = ((size_t)blockIdx.x * 256 + threadIdx.x) * 8;
    float4 a = *(const float4*)(X + i);
    float4 b = *(const float4*)(X + i + 4);
    short8 o;
    o[0] = (short)f2bf(a.x); o[1] = (short)f2bf(a.y);
    o[2] = (short)f2bf(a.z); o[3] = (short)f2bf(a.w);
    o[4] = (short)f2bf(b.x); o[5] = (short)f2bf(b.y);
    o[6] = (short)f2bf(b.z); o[7] = (short)f2bf(b.w);
    *(short8*)(Xh + i) = o;
}

// ======================= weight prep: split+transpose ======================
// Wt[z][half][n][k] bf16, z in {q,k,v}. hi = bf16(W), lo = bf16(W - hi).
__global__ void prep_w_kernel(const float* __restrict__ Wq,
                              const float* __restrict__ Wk,
                              const float* __restrict__ Wv,
                              unsigned short* __restrict__ Wt)
{
    const int z = blockIdx.y;
    const int k = blockIdx.x;      // 0..255
    const int n = threadIdx.x;     // 0..255
    const float* W = (z == 0) ? Wq : (z == 1) ? Wk : Wv;
    float w = W[k * 256 + n];
    unsigned short hi = f2bf(w);
    unsigned short lo = f2bf(w - bf2f(hi));
    size_t base = (size_t)z * 131072;
    Wt[base +         (size_t)n * 256 + k] = hi;
    Wt[base + 65536 + (size_t)n * 256 + k] = lo;
}

// ======================= QKV GEMM: C = xh@Wh + xh@Wl (bf16 MFMA) ===========
// 128x128 tile, 4 waves each a 64x64 quadrant of 4x4 16x16x32 MFMA tiles.
// A pre-converted bf16, staged via global_load_lds width=16; no in-loop VALU.
__global__ __launch_bounds__(256, 2)
void qkv_mfma_kernel(const unsigned short* __restrict__ Xh,
                     const unsigned short* __restrict__ Wt,
                     const float* __restrict__ bq, const float* __restrict__ bk,
                     const float* __restrict__ bv,
                     unsigned short* __restrict__ Q, unsigned short* __restrict__ Kp,
                     unsigned short* __restrict__ V)
{
    const int z = blockIdx.z;
    const unsigned short* Wz = Wt + (size_t)z * 131072;
    const float* bias = (z == 0) ? bq : (z == 1) ? bk : bv;
    unsigned short* Y = (z == 0) ? Q : (z == 1) ? Kp : V;

    __shared__ __align__(16) unsigned char smem[32768];
    unsigned short* Asm = (unsigned short*)smem;            // [128][32] bf16, 8 KB
    unsigned short* Bsm = (unsigned short*)(smem + 8192);   // [2][128][32] bf16, 16 KB

    const int tid = threadIdx.x;
    const int lane = tid & 63, wave = tid >> 6;
    const int wm = wave & 1, wn = wave >> 1;
    const int l15 = lane & 15, lq = lane >> 4;
    const int col0 = blockIdx.x * 128;
    const size_t row0 = (size_t)blockIdx.y * 128;

    floatx4 acc[4][4];
    #pragma unroll
    for (int i = 0; i < 4; ++i)
        #pragma unroll
        for (int j = 0; j < 4; ++j)
            acc[i][j] = (floatx4){0.f, 0.f, 0.f, 0.f};

    for (int k0 = 0; k0 < 256; k0 += 32) {
        __syncthreads();
        // A tile: [128][32] bf16 = 8 KB -> 2 x 16B per thread
        #pragma unroll
        for (int it = 0; it < 2; ++it) {
            int flat = it * 256 + tid;
            int m = flat >> 2, ks = (flat & 3) * 8;
            GLDS16(Xh + (row0 + m) * 256 + k0 + ks, Asm + flat * 8);
        }
        // B tiles: [2][128][32] bf16 = 16 KB -> 4 x 16B per thread
        #pragma unroll
        for (int half = 0; half < 2; ++half)
            #pragma unroll
            for (int it = 0; it < 2; ++it) {
                int flat = it * 256 + tid;
                int n = flat >> 2, ks = (flat & 3) * 8;
                GLDS16(Wz + half * 65536 + (size_t)(col0 + n) * 256 + k0 + ks,
                       Bsm + half * 4096 + flat * 8);
            }
        __syncthreads();

        short8 a[4];
        #pragma unroll
        for (int mt = 0; mt < 4; ++mt)
            a[mt] = *(const short8*)(Asm + (wm * 64 + mt * 16 + l15) * 32 + lq * 8);
        #pragma unroll
        for (int nt = 0; nt < 4; ++nt) {
            const unsigned short* bp = Bsm + (wn * 64 + nt * 16 + l15) * 32 + lq * 8;
            short8 bh = *(const short8*)bp;
            short8 bl = *(const short8*)(bp + 4096);
            #pragma unroll
            for (int mt = 0; mt < 4; ++mt) {
                acc[mt][nt] = __builtin_amdgcn_mfma_f32_16x16x32_bf16(a[mt], bh, acc[mt][nt], 0, 0, 0);
                acc[mt][nt] = __builtin_amdgcn_mfma_f32_16x16x32_bf16(a[mt], bl, acc[mt][nt], 0, 0, 0);
            }
        }
    }

    // ---- epilogue: bias + bf16 pack via per-wave LDS transpose ----
    __syncthreads();
    unsigned short* Cs = (unsigned short*)(smem + wave * 8192); // [64][64] bf16
    #pragma unroll
    for (int nt = 0; nt < 4; ++nt) {
        float bv_ = bias[col0 + wn * 64 + nt * 16 + l15];
        #pragma unroll
        for (int mt = 0; mt < 4; ++mt)
            #pragma unroll
            for (int r = 0; r < 4; ++r) {
                int row = mt * 16 + lq * 4 + r;
                Cs[row * 64 + nt * 16 + l15] = f2bf(acc[mt][nt][r] + bv_);
            }
    }
    #pragma unroll
    for (int p = 0; p < 8; ++p) {
        int row = p * 8 + (lane >> 3);
        float4 d = *(const float4*)(Cs + row * 64 + (lane & 7) * 8);
        *(float4*)(Y + (row0 + wm * 64 + row) * 256 + col0 + wn * 64 + (lane & 7) * 8) = d;
    }
}

// ======================= fused pool + windowed attn + gelu + reduce ========
__device__ __forceinline__ float gelu_exact(float x) {
    return 0.5f * x * (1.0f + erff(x * 0.70710678118654752f));
}

__device__ __forceinline__ void acc8(uint4 d, float* f) {
    float2 t;
    t = unpk(d.x); f[0] += t.x; f[1] += t.y;
    t = unpk(d.y); f[2] += t.x; f[3] += t.y;
    t = unpk(d.z); f[4] += t.x; f[5] += t.y;
    t = unpk(d.w); f[6] += t.x; f[7] += t.y;
}

template<int KSIZE, int LEN>
__device__ __forceinline__ void rows_for(int p, int* r, float& sc) {
    bool valid = (p < LEN);
    int pc = valid ? p : 0;
    sc = valid ? (1.0f / (float)KSIZE) : 0.0f;
    if (KSIZE == 1) { r[0] = pc; }
    else if (KSIZE == 2) {
        if (pc == 0)            { r[0] = 0;      r[1] = 1;      }
        else if (pc == LEN - 1) { r[0] = TT - 2; r[1] = TT - 1; }
        else                    { r[0] = 2 * pc - 1; r[1] = 2 * pc; }
    } else {
        if (pc == 0)            { r[0] = 2;      r[1] = 1;      r[2] = 0;      r[3] = 1;      }
        else if (pc == LEN - 1) { r[0] = TT - 3; r[1] = TT - 2; r[2] = TT - 2; r[3] = TT - 1; }
        else                    { r[0] = 4*pc - 2; r[1] = 4*pc - 1; r[2] = 4*pc; r[3] = 4*pc + 1; }
    }
}

__device__ __forceinline__ float dot8h(const float* a, const float* b) {
    float s = 0.f;
    #pragma unroll
    for (int i = 0; i < 8; ++i) s = fmaf(a[i], b[i], s);
    s += __shfl_xor(s, 1, 64);
    s += __shfl_xor(s, 2, 64);
    s += __shfl_xor(s, 4, 64);
    return s * 0.125f;   // 1/sqrt(64)
}

__device__ __forceinline__ void softmax4(const float* S, float* P) {
    float m = fmaxf(fmaxf(S[0], S[1]), fmaxf(S[2], S[3]));
    float e0 = __expf(S[0] - m), e1 = __expf(S[1] - m);
    float e2 = __expf(S[2] - m), e3 = __expf(S[3] - m);
    float inv = 1.0f / (e0 + e1 + e2 + e3);
    P[0] = e0 * inv; P[1] = e1 * inv; P[2] = e2 * inv; P[3] = e3 * inv;
}

// One wave per window-chunk; wave covers ALL 4 heads (lane l5 holds feats
// 8*l5..8*l5+7). 32-lane halves hold different tokens: pair01 = tokens
// (4w, 4w+1), pair23 = (4w+2, 4w+3); half h owns token pair_base + h.
// dwordx4 loads: 2 x 512 B segments per instruction. Pooling in-register.
template<int KSIZE, int LEN, int NWIN, int WC>
__global__ __launch_bounds__(64)
void attn_kernel(const unsigned short* __restrict__ qp,
                 const unsigned short* __restrict__ kp,
                 const unsigned short* __restrict__ vp,
                 float* __restrict__ acc)
{
    const int l = threadIdx.x;
    const int half = l >> 5, l5 = l & 31;
    const int b = blockIdx.z;
    const int w0 = blockIdx.x * WC;
    const int wend = min(w0 + WC, NWIN);
    const size_t lane_off = (size_t)b * TT * 512 + (size_t)l5 * 16;
    const char* qb = (const char*)qp + lane_off;
    const char* kb = (const char*)kp + lane_off;
    const char* vb = (const char*)vp + lane_off;

    float accv[8];
    #pragma unroll
    for (int i = 0; i < 8; ++i) accv[i] = 0.f;

    for (int w = w0; w < wend; ++w) {
        const int pA = w * 4 + half;       // token of pair01 in this half
        const int pB = pA + 2;             // token of pair23
        int rA[KSIZE], rB[KSIZE]; float sA_, sB_;
        rows_for<KSIZE, LEN>(pA, rA, sA_);
        rows_for<KSIZE, LEN>(pB, rB, sB_);

        float q01[8], q23[8], k01[8], k23[8], v01[8], v23[8];
        #pragma unroll
        for (int i = 0; i < 8; ++i) { q01[i]=0.f; q23[i]=0.f; k01[i]=0.f; k23[i]=0.f; v01[i]=0.f; v23[i]=0.f; }
        #pragma unroll
        for (int j = 0; j < KSIZE; ++j) {
            size_t oA = (size_t)rA[j] * 512, oB = (size_t)rB[j] * 512;
            acc8(*(const uint4*)(qb + oA), q01);
            acc8(*(const uint4*)(kb + oA), k01);
            acc8(*(const uint4*)(vb + oA), v01);
            acc8(*(const uint4*)(qb + oB), q23);
            acc8(*(const uint4*)(kb + oB), k23);
            acc8(*(const uint4*)(vb + oB), v23);
        }
        #pragma unroll
        for (int i = 0; i < 8; ++i) {
            q01[i] *= sA_; k01[i] *= sA_; v01[i] *= sA_;
            q23[i] *= sB_; k23[i] *= sB_; v23[i] *= sB_;
        }

        // cross-half partners (local col labels pair k/v consistently)
        float k01x[8], k23x[8], v01x[8], v23x[8];
        #pragma unroll
        for (int i = 0; i < 8; ++i) {
            k01x[i] = __shfl_xor(k01[i], 32, 64);
            k23x[i] = __shfl_xor(k23[i], 32, 64);
            v01x[i] = __shfl_xor(v01[i], 32, 64);
            v23x[i] = __shfl_xor(v23[i], 32, 64);
        }

        float SA[4], SB[4], PA[4], PB[4];
        SA[0] = dot8h(q01, k01);  SA[1] = dot8h(q01, k01x);
        SA[2] = dot8h(q01, k23);  SA[3] = dot8h(q01, k23x);
        SB[0] = dot8h(q23, k01);  SB[1] = dot8h(q23, k01x);
        SB[2] = dot8h(q23, k23);  SB[3] = dot8h(q23, k23x);
        softmax4(SA, PA);
        softmax4(SB, PB);

        float cA = 0.f, cB = 0.f;
        if (KSIZE == 1) { cA = 1.f; cB = 1.f; }
        else {
            if (pA < LEN) cA = (float)(((pA + 1) * TT + LEN - 1) / LEN - (pA * TT + LEN - 1) / LEN);
            if (pB < LEN) cB = (float)(((pB + 1) * TT + LEN - 1) / LEN - (pB * TT + LEN - 1) / LEN);
        }
        #pragma unroll
        for (int i = 0; i < 8; ++i) {
            float oA = PA[0]*v01[i] + PA[1]*v01x[i] + PA[2]*v23[i] + PA[3]*v23x[i];
            float oB = PB[0]*v01[i] + PB[1]*v01x[i] + PB[2]*v23[i] + PB[3]*v23x[i];
            accv[i] += cA * gelu_exact(oA) + cB * gelu_exact(oB);
        }
    }

    // combine halves (each half accumulated its 2 rows for the same feats)
    #pragma unroll
    for (int i = 0; i < 8; ++i) accv[i] += __shfl_xor(accv[i], 32, 64);
    if (half == 0) {
        #pragma unroll
        for (int i = 0; i < 8; ++i)
            atomicAdd(&acc[b * DD + l5 * 8 + i], accv[i]);
    }
}

// ======================= classifier head ===================================
__global__ __launch_bounds__(256)
void classifier_kernel(const float* __restrict__ acc,
                       const float* __restrict__ Wp,  const float* __restrict__ bp,
                       const float* __restrict__ Wc1, const float* __restrict__ bc1,
                       const float* __restrict__ Wc2, const float* __restrict__ bc2,
                       float* __restrict__ out)
{
    const int b = blockIdx.x;
    const int d = threadIdx.x;
    __shared__ float sm[256], sf[256], sh[256];

    sm[d] = acc[b * 256 + d] * (1.0f / 4096.0f);
    __syncthreads();

    float s = bp[d];
    for (int kk = 0; kk < 256; ++kk) s = fmaf(sm[kk], Wp[kk * 256 + d], s);
    sf[d] = s;
    __syncthreads();

    s = bc1[d];
    for (int kk = 0; kk < 256; ++kk) s = fmaf(sf[kk], Wc1[kk * 256 + d], s);
    sh[d] = fmaxf(s, 0.0f);
    __syncthreads();

    if (d < 7) {
        s = bc2[d];
        for (int kk = 0; kk < 256; ++kk) s = fmaf(sh[kk], Wc2[kk * 7 + d], s);
        out[b * 7 + d] = s;
    }
}

// ======================= launch ============================================
extern "C" void kernel_launch(void* const* d_in, const int* in_sizes, int n_in,
                              void* d_out, int out_size, void* d_ws, size_t ws_size,
                              hipStream_t stream)
{
    const float* x   = (const float*)d_in[0];
    const float* Wq  = (const float*)d_in[1];
    const float* bq  = (const float*)d_in[2];
    const float* Wk  = (const float*)d_in[3];
    const float* bk  = (const float*)d_in[4];
    const float* Wv  = (const float*)d_in[5];
    const float* bv  = (const float*)d_in[6];
    const float* Wp  = (const float*)d_in[7];
    const float* bp  = (const float*)d_in[8];
    const float* Wc1 = (const float*)d_in[9];
    const float* bc1 = (const float*)d_in[10];
    const float* Wc2 = (const float*)d_in[11];
    const float* bc2 = (const float*)d_in[12];
    float* out = (float*)d_out;

    const size_t plane = (size_t)BB * TT * DD;        // 33,554,432 elems
    unsigned short* Q  = (unsigned short*)d_ws;        // bf16 planes
    unsigned short* K  = Q + plane;
    unsigned short* V  = K + plane;
    unsigned short* Xh = V + plane;                    // bf16 X
    unsigned short* Wt = Xh + plane;                   // [3][2][256][256] bf16
    float* acc = (float*)(Wt + 3 * 131072);            // [32][256] fp32

    prep_x_kernel<<<dim3(16384), 256, 0, stream>>>(x, Xh);
    prep_w_kernel<<<dim3(256, 3), 256, 0, stream>>>(Wq, Wk, Wv, Wt);
    (void)hipMemsetAsync(acc, 0, BB * DD * sizeof(float), stream);

    qkv_mfma_kernel<<<dim3(2, 1024, 3), 256, 0, stream>>>(
        Xh, Wt, bq, bk, bv, Q, K, V);

    attn_kernel<1, 4096, 1024, 4><<<dim3(256, 1, BB), 64, 0, stream>>>(Q, K, V, acc);
    attn_kernel<2, 2049,  513, 4><<<dim3(129, 1, BB), 64, 0, stream>>>(Q, K, V, acc);
    attn_kernel<4, 1025,  257, 2><<<dim3(129, 1, BB), 64, 0, stream>>>(Q, K, V, acc);

    classifier_kernel<<<dim3(BB), 256, 0, stream>>>(acc, Wp, bp, Wc1, bc1, Wc2, bc2, out);
}

// Round 4
// 531.701 us; speedup vs baseline: 1.3354x; 1.3354x over previous
//
#include <hip/hip_runtime.h>

#define DD 256
#define TT 4096
#define BB 32

typedef __attribute__((ext_vector_type(8))) short short8;   // 8 bf16 (4 VGPR)
typedef __attribute__((ext_vector_type(4))) float floatx4;  // MFMA acc

// ---------- bf16 helpers (RNE via bit twiddle) ----------
__device__ __forceinline__ unsigned short f2bf(float f) {
    unsigned u = __builtin_bit_cast(unsigned, f);
    unsigned r = u + 0x7FFFu + ((u >> 16) & 1u);
    return (unsigned short)(r >> 16);
}
__device__ __forceinline__ float bf2f(unsigned short h) {
    return __builtin_bit_cast(float, (unsigned)h << 16);
}
__device__ __forceinline__ float2 unpk(unsigned u) {
    float2 r;
    r.x = __builtin_bit_cast(float, u << 16);
    r.y = __builtin_bit_cast(float, u & 0xFFFF0000u);
    return r;
}

#define GLDS16(g, l)                                                        \
    __builtin_amdgcn_global_load_lds(                                       \
        (const __attribute__((address_space(1))) void*)(g),                 \
        (__attribute__((address_space(3))) void*)(l), 16, 0, 0)

// ======================= X prep: fp32 -> bf16 ==============================
__global__ __launch_bounds__(256)
void prep_x_kernel(const float* __restrict__ X, unsigned short* __restrict__ Xh)
{
    size_t i = ((size_t)blockIdx.x * 256 + threadIdx.x) * 8;
    float4 a = *(const float4*)(X + i);
    float4 b = *(const float4*)(X + i + 4);
    short8 o;
    o[0] = (short)f2bf(a.x); o[1] = (short)f2bf(a.y);
    o[2] = (short)f2bf(a.z); o[3] = (short)f2bf(a.w);
    o[4] = (short)f2bf(b.x); o[5] = (short)f2bf(b.y);
    o[6] = (short)f2bf(b.z); o[7] = (short)f2bf(b.w);
    *(short8*)(Xh + i) = o;
}

// ======================= weight prep: split+transpose ======================
__global__ void prep_w_kernel(const float* __restrict__ Wq,
                              const float* __restrict__ Wk,
                              const float* __restrict__ Wv,
                              unsigned short* __restrict__ Wt)
{
    const int z = blockIdx.y;
    const int k = blockIdx.x;
    const int n = threadIdx.x;
    const float* W = (z == 0) ? Wq : (z == 1) ? Wk : Wv;
    float w = W[k * 256 + n];
    unsigned short hi = f2bf(w);
    unsigned short lo = f2bf(w - bf2f(hi));
    size_t base = (size_t)z * 131072;
    Wt[base +         (size_t)n * 256 + k] = hi;
    Wt[base + 65536 + (size_t)n * 256 + k] = lo;
}

// ======================= QKV GEMM: C = xh@Wh + xh@Wl (bf16 MFMA) ===========
__global__ __launch_bounds__(256, 2)
void qkv_mfma_kernel(const unsigned short* __restrict__ Xh,
                     const unsigned short* __restrict__ Wt,
                     const float* __restrict__ bq, const float* __restrict__ bk,
                     const float* __restrict__ bv,
                     unsigned short* __restrict__ Q, unsigned short* __restrict__ Kp,
                     unsigned short* __restrict__ V)
{
    const int z = blockIdx.z;
    const unsigned short* Wz = Wt + (size_t)z * 131072;
    const float* bias = (z == 0) ? bq : (z == 1) ? bk : bv;
    unsigned short* Y = (z == 0) ? Q : (z == 1) ? Kp : V;

    __shared__ __align__(16) unsigned char smem[32768];
    unsigned short* Asm = (unsigned short*)smem;            // [128][32] bf16, 8 KB
    unsigned short* Bsm = (unsigned short*)(smem + 8192);   // [2][128][32] bf16, 16 KB

    const int tid = threadIdx.x;
    const int lane = tid & 63, wave = tid >> 6;
    const int wm = wave & 1, wn = wave >> 1;
    const int l15 = lane & 15, lq = lane >> 4;
    const int col0 = blockIdx.x * 128;
    const size_t row0 = (size_t)blockIdx.y * 128;

    floatx4 acc[4][4];
    #pragma unroll
    for (int i = 0; i < 4; ++i)
        #pragma unroll
        for (int j = 0; j < 4; ++j)
            acc[i][j] = (floatx4){0.f, 0.f, 0.f, 0.f};

    for (int k0 = 0; k0 < 256; k0 += 32) {
        __syncthreads();
        #pragma unroll
        for (int it = 0; it < 2; ++it) {
            int flat = it * 256 + tid;
            int m = flat >> 2, ks = (flat & 3) * 8;
            GLDS16(Xh + (row0 + m) * 256 + k0 + ks, Asm + flat * 8);
        }
        #pragma unroll
        for (int half = 0; half < 2; ++half)
            #pragma unroll
            for (int it = 0; it < 2; ++it) {
                int flat = it * 256 + tid;
                int n = flat >> 2, ks = (flat & 3) * 8;
                GLDS16(Wz + half * 65536 + (size_t)(col0 + n) * 256 + k0 + ks,
                       Bsm + half * 4096 + flat * 8);
            }
        __syncthreads();

        short8 a[4];
        #pragma unroll
        for (int mt = 0; mt < 4; ++mt)
            a[mt] = *(const short8*)(Asm + (wm * 64 + mt * 16 + l15) * 32 + lq * 8);
        #pragma unroll
        for (int nt = 0; nt < 4; ++nt) {
            const unsigned short* bp = Bsm + (wn * 64 + nt * 16 + l15) * 32 + lq * 8;
            short8 bh = *(const short8*)bp;
            short8 bl = *(const short8*)(bp + 4096);
            #pragma unroll
            for (int mt = 0; mt < 4; ++mt) {
                acc[mt][nt] = __builtin_amdgcn_mfma_f32_16x16x32_bf16(a[mt], bh, acc[mt][nt], 0, 0, 0);
                acc[mt][nt] = __builtin_amdgcn_mfma_f32_16x16x32_bf16(a[mt], bl, acc[mt][nt], 0, 0, 0);
            }
        }
    }

    __syncthreads();
    unsigned short* Cs = (unsigned short*)(smem + wave * 8192); // [64][64] bf16
    #pragma unroll
    for (int nt = 0; nt < 4; ++nt) {
        float bv_ = bias[col0 + wn * 64 + nt * 16 + l15];
        #pragma unroll
        for (int mt = 0; mt < 4; ++mt)
            #pragma unroll
            for (int r = 0; r < 4; ++r) {
                int row = mt * 16 + lq * 4 + r;
                Cs[row * 64 + nt * 16 + l15] = f2bf(acc[mt][nt][r] + bv_);
            }
    }
    #pragma unroll
    for (int p = 0; p < 8; ++p) {
        int row = p * 8 + (lane >> 3);
        float4 d = *(const float4*)(Cs + row * 64 + (lane & 7) * 8);
        *(float4*)(Y + (row0 + wm * 64 + row) * 256 + col0 + wn * 64 + (lane & 7) * 8) = d;
    }
}

// ======================= fused 3-scale attention ===========================
__device__ __forceinline__ float gelu_exact(float x) {
    return 0.5f * x * (1.0f + erff(x * 0.70710678118654752f));
}
__device__ __forceinline__ void addu4(uint4 d, float* f) {
    float2 t;
    t = unpk(d.x); f[0] += t.x; f[1] += t.y;
    t = unpk(d.y); f[2] += t.x; f[3] += t.y;
    t = unpk(d.z); f[4] += t.x; f[5] += t.y;
    t = unpk(d.w); f[6] += t.x; f[7] += t.y;
}

#define SPAN 32
#define NROW 34            // span + 2 leading ghost rows
#define STR  264           // bf16 row stride in LDS (16B-aligned, quad-spreading)

// Block = (span s, batch b). 256 threads = 64 units x 4 lanes.
// Unit = (scale, window, head); unit-lane covers 16 of the head's 64 feats.
// All 3 scales consume the same LDS tile (rows r0-2 .. r0+31).
__global__ __launch_bounds__(256, 2)
void attn_fused_kernel(const unsigned short* __restrict__ Q,
                       const unsigned short* __restrict__ K,
                       const unsigned short* __restrict__ V,
                       float* __restrict__ acc)
{
    __shared__ __align__(16) unsigned char smem[3 * NROW * STR * 2];  // 53856 B
    unsigned short* qkvs = (unsigned short*)smem;       // [3][NROW][STR]
    float* scratch = (float*)smem;                      // [16][256] overlay (post-barrier)

    const int tid = threadIdx.x;
    const int s = blockIdx.x;          // span within batch (0..127)
    const int b = blockIdx.y;
    const int r0 = s * SPAN;

    // ---- load phase: 3 x 34 rows x 512 B ----
    #pragma unroll
    for (int t = 0; t < 3; ++t) {
        const unsigned short* src = ((t == 0) ? Q : (t == 1) ? K : V) + (size_t)b * TT * DD;
        #pragma unroll
        for (int it = 0; it < 5; ++it) {
            int flat = it * 256 + tid;              // 0..1279, need 0..1087
            if (flat < NROW * 32) {
                int row = flat >> 5, c = flat & 31;
                int g = r0 - 2 + row;
                g = (g < 0) ? 0 : g;                 // only span 0 clamps (unused rows)
                uint4 d = *(const uint4*)(src + (size_t)g * DD + c * 8);
                *(uint4*)(qkvs + t * (NROW * STR) + row * STR + c * 8) = d;
            }
        }
    }
    __syncthreads();

    // ---- unit decode (waves are scale-uniform) ----
    const int slot = tid >> 2, lq = tid & 3;
    const int head = slot & 3, u = slot >> 2;     // u = 0..15
    int ksize, LEN, w; bool active = true;
    if (u < 8)       { ksize = 1; LEN = 4096; w = s * 8 + u; }
    else if (u < 12) { ksize = 2; LEN = 2049; w = s * 4 + (u - 8); }
    else if (u < 14) { ksize = 4; LEN = 1025; w = s * 2 + (u - 12); }
    else if (u == 14){ ksize = 2; LEN = 2049; w = 512; active = (s == 127); }
    else             { ksize = 4; LEN = 1025; w = 256; active = (s == 127); }

    const int f0 = head * 64 + lq * 16;
    float accL[16];
    #pragma unroll
    for (int i = 0; i < 16; ++i) accL[i] = 0.f;

    if (active) {
        int ridx[4][4]; float cw[4]; bool val[4];
        for (int i = 0; i < 4; ++i) {
            int p = w * 4 + i;
            val[i] = (p < LEN);
            int pc = val[i] ? p : 0;
            int r[4] = {0, 0, 0, 0};
            if (ksize == 1) { r[0] = pc; }
            else if (ksize == 2) {
                if (pc == 0)            { r[0] = 0;      r[1] = 1;      }
                else if (pc == LEN - 1) { r[0] = TT - 2; r[1] = TT - 1; }
                else                    { r[0] = 2 * pc - 1; r[1] = 2 * pc; }
            } else {
                if (pc == 0)            { r[0] = 2; r[1] = 1; r[2] = 0; r[3] = 1; }
                else if (pc == LEN - 1) { r[0] = TT - 3; r[1] = TT - 2; r[2] = TT - 2; r[3] = TT - 1; }
                else                    { r[0] = 4*pc - 2; r[1] = 4*pc - 1; r[2] = 4*pc; r[3] = 4*pc + 1; }
            }
            #pragma unroll
            for (int j = 0; j < 4; ++j) ridx[i][j] = r[j] - (r0 - 2);
            float c = 1.f;
            if (ksize != 1)
                c = (float)(((p + 1) * TT + LEN - 1) / LEN - (p * TT + LEN - 1) / LEN);
            cw[i] = val[i] ? c : 0.f;
        }
        const float inv_k = 1.0f / (float)ksize;

        // scores, feats processed in two 8-wide halves
        float S[4][4];
        #pragma unroll
        for (int i = 0; i < 4; ++i)
            #pragma unroll
            for (int j = 0; j < 4; ++j) S[i][j] = 0.f;

        for (int half = 0; half < 2; ++half) {
            float qf[4][8], kf[4][8];
            for (int i = 0; i < 4; ++i) {
                #pragma unroll
                for (int e = 0; e < 8; ++e) { qf[i][e] = 0.f; kf[i][e] = 0.f; }
                if (val[i])
                    for (int j = 0; j < ksize; ++j) {
                        int off = ridx[i][j] * STR + f0 + half * 8;
                        addu4(*(const uint4*)(qkvs + off), qf[i]);
                        addu4(*(const uint4*)(qkvs + NROW * STR + off), kf[i]);
                    }
                #pragma unroll
                for (int e = 0; e < 8; ++e) { qf[i][e] *= inv_k; kf[i][e] *= inv_k; }
            }
            #pragma unroll
            for (int i = 0; i < 4; ++i)
                #pragma unroll
                for (int j = 0; j < 4; ++j) {
                    float d = 0.f;
                    #pragma unroll
                    for (int e = 0; e < 8; ++e) d = fmaf(qf[i][e], kf[j][e], d);
                    S[i][j] += d;
                }
        }
        // reduce over the unit's 4 lanes (feats 0..63), scale by 1/sqrt(64)
        #pragma unroll
        for (int i = 0; i < 4; ++i)
            #pragma unroll
            for (int j = 0; j < 4; ++j) {
                float t = S[i][j];
                t += __shfl_xor(t, 1, 64);
                t += __shfl_xor(t, 2, 64);
                S[i][j] = t * 0.125f;
            }
        float P[4][4];
        #pragma unroll
        for (int i = 0; i < 4; ++i) {
            float m = fmaxf(fmaxf(S[i][0], S[i][1]), fmaxf(S[i][2], S[i][3]));
            float e0 = __expf(S[i][0] - m), e1 = __expf(S[i][1] - m);
            float e2 = __expf(S[i][2] - m), e3 = __expf(S[i][3] - m);
            float inv = 1.0f / (e0 + e1 + e2 + e3);
            P[i][0] = e0 * inv; P[i][1] = e1 * inv; P[i][2] = e2 * inv; P[i][3] = e3 * inv;
        }
        // PV + gelu + repeat-count weighting
        for (int half = 0; half < 2; ++half) {
            float vf[4][8];
            for (int i = 0; i < 4; ++i) {
                #pragma unroll
                for (int e = 0; e < 8; ++e) vf[i][e] = 0.f;
                if (val[i])
                    for (int j = 0; j < ksize; ++j) {
                        int off = ridx[i][j] * STR + f0 + half * 8;
                        addu4(*(const uint4*)(qkvs + 2 * NROW * STR + off), vf[i]);
                    }
                #pragma unroll
                for (int e = 0; e < 8; ++e) vf[i][e] *= inv_k;
            }
            #pragma unroll
            for (int i = 0; i < 4; ++i) {
                if (!val[i]) continue;
                #pragma unroll
                for (int e = 0; e < 8; ++e) {
                    float o = P[i][0]*vf[0][e] + P[i][1]*vf[1][e]
                            + P[i][2]*vf[2][e] + P[i][3]*vf[3][e];
                    accL[half * 8 + e] += cw[i] * gelu_exact(o);
                }
            }
        }
    }

    // ---- block reduction over the 16 window-units, one atomic per feat ----
    __syncthreads();   // all qkvs reads done; reuse LDS as scratch
    #pragma unroll
    for (int e = 0; e < 16; e += 4) {
        float4 d = {accL[e], accL[e+1], accL[e+2], accL[e+3]};
        *(float4*)(scratch + u * 256 + f0 + e) = d;
    }
    __syncthreads();
    float sum = 0.f;
    #pragma unroll
    for (int uu = 0; uu < 16; ++uu) sum += scratch[uu * 256 + tid];
    atomicAdd(&acc[b * DD + tid], sum);
}

// ======================= classifier head ===================================
__global__ __launch_bounds__(256)
void classifier_kernel(const float* __restrict__ acc,
                       const float* __restrict__ Wp,  const float* __restrict__ bp,
                       const float* __restrict__ Wc1, const float* __restrict__ bc1,
                       const float* __restrict__ Wc2, const float* __restrict__ bc2,
                       float* __restrict__ out)
{
    const int b = blockIdx.x;
    const int d = threadIdx.x;
    __shared__ float sm[256], sf[256], sh[256];

    sm[d] = acc[b * 256 + d] * (1.0f / 4096.0f);
    __syncthreads();

    float s = bp[d];
    for (int kk = 0; kk < 256; ++kk) s = fmaf(sm[kk], Wp[kk * 256 + d], s);
    sf[d] = s;
    __syncthreads();

    s = bc1[d];
    for (int kk = 0; kk < 256; ++kk) s = fmaf(sf[kk], Wc1[kk * 256 + d], s);
    sh[d] = fmaxf(s, 0.0f);
    __syncthreads();

    if (d < 7) {
        s = bc2[d];
        for (int kk = 0; kk < 256; ++kk) s = fmaf(sh[kk], Wc2[kk * 7 + d], s);
        out[b * 7 + d] = s;
    }
}

// ======================= launch ============================================
extern "C" void kernel_launch(void* const* d_in, const int* in_sizes, int n_in,
                              void* d_out, int out_size, void* d_ws, size_t ws_size,
                              hipStream_t stream)
{
    const float* x   = (const float*)d_in[0];
    const float* Wq  = (const float*)d_in[1];
    const float* bq  = (const float*)d_in[2];
    const float* Wk  = (const float*)d_in[3];
    const float* bk  = (const float*)d_in[4];
    const float* Wv  = (const float*)d_in[5];
    const float* bv  = (const float*)d_in[6];
    const float* Wp  = (const float*)d_in[7];
    const float* bp  = (const float*)d_in[8];
    const float* Wc1 = (const float*)d_in[9];
    const float* bc1 = (const float*)d_in[10];
    const float* Wc2 = (const float*)d_in[11];
    const float* bc2 = (const float*)d_in[12];
    float* out = (float*)d_out;

    const size_t plane = (size_t)BB * TT * DD;
    unsigned short* Q  = (unsigned short*)d_ws;
    unsigned short* K  = Q + plane;
    unsigned short* V  = K + plane;
    unsigned short* Xh = V + plane;
    unsigned short* Wt = Xh + plane;
    float* acc = (float*)(Wt + 3 * 131072);

    prep_x_kernel<<<dim3(16384), 256, 0, stream>>>(x, Xh);
    prep_w_kernel<<<dim3(256, 3), 256, 0, stream>>>(Wq, Wk, Wv, Wt);
    (void)hipMemsetAsync(acc, 0, BB * DD * sizeof(float), stream);

    qkv_mfma_kernel<<<dim3(2, 1024, 3), 256, 0, stream>>>(
        Xh, Wt, bq, bk, bv, Q, K, V);

    attn_fused_kernel<<<dim3(128, BB), 256, 0, stream>>>(Q, K, V, acc);

    classifier_kernel<<<dim3(BB), 256, 0, stream>>>(acc, Wp, bp, Wc1, bc1, Wc2, bc2, out);
}